// Round 12
// baseline (33.955 us; speedup 1.0000x reference)
//
#include <hip/hip_runtime.h>
#include <hip/hip_bf16.h>

typedef __attribute__((ext_vector_type(8))) short short8;
typedef __attribute__((ext_vector_type(4))) short short4v;
typedef __attribute__((ext_vector_type(4))) float floatx4;
typedef __attribute__((ext_vector_type(4))) unsigned int uintx4;
typedef __attribute__((ext_vector_type(4))) int intx4;
typedef unsigned int u32;
typedef unsigned short u16;

#define NB 1024
#define ND 16
#define NM 4
#define NR 4096
#define NC 64
#define EPSF 1e-9f
#define KS 16  // gemm k-splits

__device__ inline u16 f2bf(float f) {
    u32 u;
    __builtin_memcpy(&u, &f, 4);
    u32 lsb = (u >> 16) & 1;
    u += 0x7fffu + lsb;   // round-to-nearest-even
    return (u16)(u >> 16);
}

// ---- Kernel 1 (tiny): pack rules -> 2 bits x 16 dims per u32 ----
__global__ __launch_bounds__(256) void k_pack(const int* __restrict__ rules,
                                              u32* __restrict__ packed) {
    int r = blockIdx.x * 256 + threadIdx.x;
    const int* q = rules + (size_t)r * ND;
    u32 pk = 0;
#pragma unroll
    for (int i = 0; i < 4; ++i) {
        intx4 v = *(const intx4*)(q + i * 4);
#pragma unroll
        for (int e = 0; e < 4; ++e) pk |= ((u32)(v[e] & 3)) << (2 * (i * 4 + e));
    }
    packed[r] = pk;
}

// ---- Kernel 2: blocks 0..127 cons-reduce (32 rules each); 128..1151 per-b fs ----
__global__ __launch_bounds__(512) void k_mid(const float* __restrict__ cons,
                                             const float* __restrict__ x,
                                             const float* __restrict__ centers,
                                             const float* __restrict__ widths,
                                             const u32* __restrict__ packed,
                                             u16* __restrict__ s_consT,
                                             float* __restrict__ out_nfs,
                                             float* __restrict__ out_xe,
                                             float* __restrict__ sx) {
    __shared__ u16 tile[32][68];
    __shared__ float xv[16];
    __shared__ float mftab[64];
    __shared__ float gtab[1024];
    __shared__ float wred[8];
    __shared__ float s_inv;
    int bid = blockIdx.x;
    int tid = threadIdx.x;
    if (bid < 128) {
        // prep: s_consT[c][r] = bf16(sum_j cons[r,j,c]), 32 rules per block
        int rbase = bid * 32;
        int c = tid & 63;
        int rr = tid >> 6;  // 0..7
#pragma unroll
        for (int it = 0; it < 4; ++it, rr += 8) {
            const float* p = cons + (size_t)(rbase + rr) * (ND + 1) * NC + c;
            float s = 0.f;
#pragma unroll
            for (int j = 0; j < ND + 1; ++j) s += p[j * NC];
            tile[rr][c] = f2bf(s);
        }
        __syncthreads();
        int cc = tid >> 3;          // 0..63
        int r0 = (tid & 7) * 4;     // 0..28
        short4v v;
#pragma unroll
        for (int e = 0; e < 4; ++e) v[e] = (short)tile[r0 + e][cc];
        *(short4v*)(s_consT + (size_t)cc * NR + rbase + r0) = v;
        return;
    }
    // fs path: one batch row, 512 threads, 8 consecutive rules/thread
    int b = bid - 128;
    if (tid < 16) {
        float raw = x[b * 16 + tid];
        xv[tid] = raw;
        out_xe[b * 17 + tid] = raw;
    }
    if (tid == 16) out_xe[b * 17 + 16] = 1.0f;
    __syncthreads();
    if (tid < 64) {
        float diff = xv[tid >> 2] - centers[tid];
        float w = widths[tid];
        mftab[tid] = __expf(-diff * diff / (2.f * w * w)) + EPSF;
    }
    __syncthreads();
#pragma unroll
    for (int it = 0; it < 2; ++it) {
        int idx = it * 512 + tid;
        int g = idx >> 8, i = idx & 255;
        const float* mf = mftab + g * 16;
        gtab[idx] = mf[0 + (i & 3)] * mf[4 + ((i >> 2) & 3)] *
                    mf[8 + ((i >> 4) & 3)] * mf[12 + ((i >> 6) & 3)];
    }
    __syncthreads();
    int r0 = tid * 8;
    floatx4 f[2];
    float lsum = 0.f;
#pragma unroll
    for (int it = 0; it < 2; ++it) {
        uintx4 p = *(const uintx4*)(packed + r0 + it * 4);
#pragma unroll
        for (int e = 0; e < 4; ++e) {
            u32 pk = p[e];
            f[it][e] = gtab[pk & 255] * gtab[256 + ((pk >> 8) & 255)] *
                       gtab[512 + ((pk >> 16) & 255)] * gtab[768 + (pk >> 24)];
            lsum += f[it][e];
        }
    }
    for (int off = 32; off; off >>= 1) lsum += __shfl_down(lsum, off, 64);
    if ((tid & 63) == 0) wred[tid >> 6] = lsum;
    __syncthreads();
    if (tid == 0) {
        float t = 0.f;
#pragma unroll
        for (int i = 0; i < 8; ++i) t += wred[i];
        s_inv = 1.f / (t + EPSF);
    }
    __syncthreads();
    float inv = s_inv;
    if (tid == 0) {
        float s = 1.f;
#pragma unroll
        for (int i = 0; i < 16; ++i) s += xv[i];
        sx[b] = s;
    }
    float* on = out_nfs + (size_t)b * NR + r0;
#pragma unroll
    for (int it = 0; it < 2; ++it) {
        floatx4 v;
#pragma unroll
        for (int e = 0; e < 4; ++e) v[e] = f[it][e] * inv;
        *(floatx4*)(on + it * 4) = v;
    }
}

// ---- Kernel 3: nfs fp32 -> bf16 in-reg, MFMA; 8 waves = 2 rsub x 4 kq; LDS reduce ----
__global__ __launch_bounds__(512) void k_gemm(const float* __restrict__ nfs,
                                              const u16* __restrict__ s_consT,
                                              float* __restrict__ part) {
    __shared__ float red[3][2][16][64];   // kq 1..3 deposit
    int rt = blockIdx.x;   // 32 row-tiles of 32
    int ks = blockIdx.y;   // 16 k-splits of 256
    int tid = threadIdx.x;
    int wid = tid >> 6, lane = tid & 63;
    int rsub = wid & 1, kq = wid >> 1;   // 2 row-halves x 4 k-quarters
    int row = rt * 32 + rsub * 16 + (lane & 15);
    int k0 = ks * 256 + kq * 64 + (lane >> 4) * 8;
    const float* aptr = nfs + (size_t)row * NR + k0;
    const u16* bptr = s_consT + (size_t)(lane & 15) * NR + k0;

    // fully prefetch both K-steps (t = 0, 32)
    floatx4 a00 = *(const floatx4*)(aptr);
    floatx4 a01 = *(const floatx4*)(aptr + 4);
    floatx4 a10 = *(const floatx4*)(aptr + 32);
    floatx4 a11 = *(const floatx4*)(aptr + 36);
    short8 b0[4], b1[4];
#pragma unroll
    for (int cb = 0; cb < 4; ++cb) {
        b0[cb] = *(const short8*)(bptr + (size_t)cb * 16 * NR);
        b1[cb] = *(const short8*)(bptr + (size_t)cb * 16 * NR + 32);
    }
    short8 af0, af1;
#pragma unroll
    for (int e = 0; e < 4; ++e) {
        af0[e] = (short)f2bf(a00[e]);
        af0[e + 4] = (short)f2bf(a01[e]);
        af1[e] = (short)f2bf(a10[e]);
        af1[e + 4] = (short)f2bf(a11[e]);
    }
    floatx4 acc[4] = {};
#pragma unroll
    for (int cb = 0; cb < 4; ++cb) {
        acc[cb] = __builtin_amdgcn_mfma_f32_16x16x32_bf16(af0, b0[cb], acc[cb], 0, 0, 0);
        acc[cb] = __builtin_amdgcn_mfma_f32_16x16x32_bf16(af1, b1[cb], acc[cb], 0, 0, 0);
    }
    int rloc = (lane >> 4) * 4;
    if (kq > 0) {
#pragma unroll
        for (int cb = 0; cb < 4; ++cb)
#pragma unroll
            for (int reg = 0; reg < 4; ++reg)
                red[kq - 1][rsub][rloc + reg][cb * 16 + (lane & 15)] = acc[cb][reg];
    }
    __syncthreads();
    if (kq == 0) {
        float* po = part + (size_t)ks * (NB * NC);
#pragma unroll
        for (int cb = 0; cb < 4; ++cb)
#pragma unroll
            for (int reg = 0; reg < 4; ++reg) {
                int rr = rloc + reg, cc = cb * 16 + (lane & 15);
                float v = acc[cb][reg] + red[0][rsub][rr][cc] +
                          red[1][rsub][rr][cc] + red[2][rsub][rr][cc];
                po[(size_t)(rt * 32 + rsub * 16 + rr) * NC + cc] = v;
            }
    }
}

// ---- Kernel 4: reduce K-splits, scale by sx ----
__global__ __launch_bounds__(256) void k_out(const float* __restrict__ part,
                                             const float* __restrict__ sx,
                                             float* __restrict__ out0) {
    int t = blockIdx.x * 256 + threadIdx.x;
    float a = 0.f;
#pragma unroll
    for (int ks = 0; ks < KS; ++ks) a += part[(size_t)ks * (NB * NC) + t];
    out0[t] = a * sx[t >> 6];
}

extern "C" void kernel_launch(void* const* d_in, const int* in_sizes, int n_in,
                              void* d_out, int out_size, void* d_ws, size_t ws_size,
                              hipStream_t stream) {
    const float* x = (const float*)d_in[0];
    const float* centers = (const float*)d_in[1];
    const float* widths = (const float*)d_in[2];
    const float* cons = (const float*)d_in[3];
    const int* rules = (const int*)d_in[4];

    float* out = (float*)d_out;
    float* out_rule = out;                        // [1024,64]
    float* out_nfs = out + NB * NC;               // [1024,4096]
    float* out_xe = out + NB * NC + NB * NR;      // [1024,17]

    char* ws = (char*)d_ws;
    u16* s_consT = (u16*)ws;                                   // 512 KB
    u32* packed = (u32*)(ws + (512 << 10));                    // 16 KB
    float* sx = (float*)(ws + (512 << 10) + (16 << 10));       // 4 KB
    float* part = (float*)(ws + (512 << 10) + (24 << 10));     // 16*256KB = 4 MB

    k_pack<<<NR / 256, 256, 0, stream>>>(rules, packed);
    k_mid<<<128 + NB, 512, 0, stream>>>(cons, x, centers, widths, packed,
                                        s_consT, out_nfs, out_xe, sx);
    k_gemm<<<dim3(32, KS), 512, 0, stream>>>(out_nfs, s_consT, part);
    k_out<<<(NB * NC) / 256, 256, 0, stream>>>(part, sx, out_rule);
}